// Round 1
// baseline (802.030 us; speedup 1.0000x reference)
//
#include <hip/hip_runtime.h>

#define F0 11
#define F1 64
#define F2 128

// ---------------- init: deg=1 (self loop), cnt=0, zero BN stats ----------------
__global__ void k_init(float* __restrict__ deg, int* __restrict__ cnt,
                       double* __restrict__ gsum, double* __restrict__ gsumsq, int n) {
  int i = blockIdx.x * blockDim.x + threadIdx.x;
  if (i < n) { deg[i] = 1.0f; cnt[i] = 0; }
  if (i < 64) { gsum[i] = 0.0; gsumsq[i] = 0.0; }
}

// ---------------- weighted degree + in-degree histogram ----------------
__global__ void k_deg(const int* __restrict__ col, const float* __restrict__ w,
                      float* __restrict__ deg, int* __restrict__ cnt, int E) {
  int e = blockIdx.x * blockDim.x + threadIdx.x;
  if (e >= E) return;
  int c = col[e];
  atomicAdd(&deg[c], w[e]);
  atomicAdd(&cnt[c], 1);
}

// deg -> dinv (deg >= 1 always because of self loops)
__global__ void k_dinv(float* __restrict__ deg, int n) {
  int i = blockIdx.x * blockDim.x + threadIdx.x;
  if (i < n) deg[i] = rsqrtf(deg[i]);
}

// ---------------- exclusive scan of cnt -> offs (3 kernels) ----------------
__global__ void k_scan1(const int* __restrict__ cnt, int* __restrict__ offs,
                        int* __restrict__ bsum, int n) {
  __shared__ int s[1024];
  int tid = threadIdx.x;
  int i = blockIdx.x * 1024 + tid;
  int v = (i < n) ? cnt[i] : 0;
  s[tid] = v;
  __syncthreads();
  for (int d = 1; d < 1024; d <<= 1) {
    int t = (tid >= d) ? s[tid - d] : 0;
    __syncthreads();
    s[tid] += t;
    __syncthreads();
  }
  if (i < n) offs[i] = s[tid] - v;            // exclusive within block
  if (tid == 1023) bsum[blockIdx.x] = s[1023]; // block total
}

__global__ void k_scan2(int* __restrict__ bsum, int nb) {
  if (threadIdx.x == 0) {
    int acc = 0;
    for (int b = 0; b < nb; b++) { int v = bsum[b]; bsum[b] = acc; acc += v; }
  }
}

__global__ void k_scan3(int* __restrict__ offs, int* __restrict__ cursor,
                        const int* __restrict__ bsum, int n, int total) {
  int i = blockIdx.x * 1024 + threadIdx.x;
  if (i < n) {
    int v = offs[i] + bsum[blockIdx.x];
    offs[i] = v;
    cursor[i] = v;   // running cursor for the scatter fill
  }
  if (i == 0) offs[n] = total;
}

// ---------------- CSR fill: group edges by destination, store (src, norm) ----------------
__global__ void k_fill(const int* __restrict__ row, const int* __restrict__ col,
                       const float* __restrict__ w, const float* __restrict__ dinv,
                       int* __restrict__ cursor, int* __restrict__ csr_src,
                       float* __restrict__ csr_nrm, int E) {
  int e = blockIdx.x * blockDim.x + threadIdx.x;
  if (e >= E) return;
  int c = col[e], r = row[e];
  int pos = atomicAdd(&cursor[c], 1);
  csr_src[pos] = r;
  csr_nrm[pos] = dinv[r] * w[e] * dinv[c];
}

// ---------------- layer-1 aggregation of raw x (11 features), wave per node ----------------
__global__ void k_agg1(const float* __restrict__ x, const int* __restrict__ offs,
                       const int* __restrict__ csr_src, const float* __restrict__ csr_nrm,
                       const float* __restrict__ dinv, float* __restrict__ agg1, int n) {
  int wid = (blockIdx.x * blockDim.x + threadIdx.x) >> 6;
  int lane = threadIdx.x & 63;
  if (wid >= n) return;
  float di = dinv[wid];
  float acc = 0.0f;
  if (lane < F0) acc = di * di * x[wid * F0 + lane];   // self loop, norm = dinv^2
  int s = offs[wid], e = offs[wid + 1];
  for (int k = s; k < e; k++) {
    int r = csr_src[k];
    float nm = csr_nrm[k];
    if (lane < F0) acc += nm * x[r * F0 + lane];
  }
  if (lane < F0) agg1[wid * F0 + lane] = acc;
}

// ---------------- h = agg1 @ W1 + b1, wave per node, lane = out feature ----------------
__global__ void k_gemm1(const float* __restrict__ agg1, const float* __restrict__ W1,
                        const float* __restrict__ b1, float* __restrict__ h, int n) {
  __shared__ float Ws[F0 * F1];
  __shared__ float bs[F1];
  int t = threadIdx.x;
  for (int i = t; i < F0 * F1; i += blockDim.x) Ws[i] = W1[i];
  if (t < F1) bs[t] = b1[t];
  __syncthreads();
  int wid = (blockIdx.x * blockDim.x + t) >> 6;
  int lane = t & 63;
  if (wid >= n) return;
  float a[F0];
#pragma unroll
  for (int k = 0; k < F0; k++) a[k] = agg1[wid * F0 + k];  // wave-uniform loads
  float acc = bs[lane];
#pragma unroll
  for (int k = 0; k < F0; k++) acc += a[k] * Ws[k * F1 + lane];
  h[wid * F1 + lane] = acc;
}

// ---------------- BatchNorm statistics (sum, sumsq per feature) ----------------
__global__ void k_bn_stats(const float* __restrict__ h, double* __restrict__ gsum,
                           double* __restrict__ gsumsq, int total) {
  int t = threadIdx.x;
  int idx = blockIdx.x * blockDim.x + t;
  int stride = gridDim.x * blockDim.x;   // multiple of 64 -> each thread's feature fixed
  float s = 0.0f, q = 0.0f;
  for (int i = idx; i < total; i += stride) {
    float v = h[i];
    s += v; q += v * v;
  }
  __shared__ float ss[256], qq[256];
  ss[t] = s; qq[t] = q;
  __syncthreads();
  if (t < 64) {
    float S = ss[t] + ss[t + 64] + ss[t + 128] + ss[t + 192];
    float Q = qq[t] + qq[t + 64] + qq[t + 128] + qq[t + 192];
    atomicAdd(&gsum[t], (double)S);
    atomicAdd(&gsumsq[t], (double)Q);
  }
}

__global__ void k_bn_final(const double* __restrict__ gsum, const double* __restrict__ gsumsq,
                           const float* __restrict__ gamma, const float* __restrict__ beta,
                           float* __restrict__ scalef, float* __restrict__ shiftf, int n) {
  int f = threadIdx.x;
  if (f >= 64) return;
  double mean = gsum[f] / (double)n;
  double var = gsumsq[f] / (double)n - mean * mean;
  if (var < 0.0) var = 0.0;
  float scale = gamma[f] * (float)(1.0 / sqrt(var + 1e-5));
  scalef[f] = scale;
  shiftf[f] = beta[f] - (float)mean * scale;
}

// ---------------- normalize + ReLU in place (float4) ----------------
__global__ void k_bn_relu(float* __restrict__ h, const float* __restrict__ scalef,
                          const float* __restrict__ shiftf, int n4) {
  int i = blockIdx.x * blockDim.x + threadIdx.x;
  if (i >= n4) return;
  float4 v = ((float4*)h)[i];
  int f = (i * 4) & 63;
  v.x = fmaxf(0.0f, v.x * scalef[f + 0] + shiftf[f + 0]);
  v.y = fmaxf(0.0f, v.y * scalef[f + 1] + shiftf[f + 1]);
  v.z = fmaxf(0.0f, v.z * scalef[f + 2] + shiftf[f + 2]);
  v.w = fmaxf(0.0f, v.w * scalef[f + 3] + shiftf[f + 3]);
  ((float4*)h)[i] = v;
}

// ---------------- layer-2 aggregation of h (64 features), wave per node ----------------
__global__ void k_agg2(const float* __restrict__ h, const int* __restrict__ offs,
                       const int* __restrict__ csr_src, const float* __restrict__ csr_nrm,
                       const float* __restrict__ dinv, float* __restrict__ agg2, int n) {
  int wid = (blockIdx.x * blockDim.x + threadIdx.x) >> 6;
  int lane = threadIdx.x & 63;
  if (wid >= n) return;
  float di = dinv[wid];
  float acc = di * di * h[wid * F1 + lane];   // self loop
  int s = offs[wid], e = offs[wid + 1];
  for (int k = s; k < e; k++) {
    int r = csr_src[k];
    float nm = csr_nrm[k];
    acc += nm * h[r * F1 + lane];             // 256B coalesced gather
  }
  agg2[wid * F1 + lane] = acc;
}

// ---------------- out = agg2 @ W2 + b2, wave per node, lane -> outputs {j, j+64} ----------------
__global__ void k_gemm2(const float* __restrict__ agg2, const float* __restrict__ W2,
                        const float* __restrict__ b2, float* __restrict__ out, int n) {
  __shared__ float Ws[F1 * F2];   // 32 KiB
  int t = threadIdx.x;
  for (int i = t; i < F1 * F2; i += blockDim.x) Ws[i] = W2[i];
  __syncthreads();
  int wid = (blockIdx.x * blockDim.x + t) >> 6;
  int lane = t & 63;
  if (wid >= n) return;
  float areg = agg2[wid * F1 + lane];
  float acc0 = b2[lane];
  float acc1 = b2[64 + lane];
#pragma unroll
  for (int f = 0; f < F1; f++) {
    float a = __shfl(areg, f);                 // constant lane after unroll -> readlane
    acc0 += a * Ws[f * F2 + lane];
    acc1 += a * Ws[f * F2 + 64 + lane];
  }
  out[wid * F2 + lane] = acc0;
  out[wid * F2 + 64 + lane] = acc1;
}

extern "C" void kernel_launch(void* const* d_in, const int* in_sizes, int n_in,
                              void* d_out, int out_size, void* d_ws, size_t ws_size,
                              hipStream_t stream) {
  const float* x     = (const float*)d_in[0];
  const int*   ei    = (const int*)d_in[1];
  const float* ew    = (const float*)d_in[2];
  const float* W1    = (const float*)d_in[3];
  const float* b1    = (const float*)d_in[4];
  const float* gamma = (const float*)d_in[5];
  const float* beta  = (const float*)d_in[6];
  const float* W2    = (const float*)d_in[7];
  const float* b2    = (const float*)d_in[8];
  float* out = (float*)d_out;

  int N = in_sizes[0] / F0;
  int E = in_sizes[1] / 2;
  const int* row = ei;       // edge_index[0]
  const int* col = ei + E;   // edge_index[1]
  if (N <= 0) return;

  // ---- workspace carve-up (~70 MB) ----
  char* p = (char*)d_ws;
  auto alloc = [&](size_t bytes) -> void* {
    void* r = (void*)p;
    p += (bytes + 255) & ~(size_t)255;
    return r;
  };
  float*  deg     = (float*)alloc((size_t)N * 4);        // becomes dinv
  int*    cnt     = (int*)alloc((size_t)N * 4);          // histogram -> cursor
  int*    offs    = (int*)alloc((size_t)(N + 1) * 4);
  int     NB      = (N + 1023) / 1024;
  int*    bsum    = (int*)alloc((size_t)NB * 4);
  int*    csr_src = (int*)alloc((size_t)E * 4);
  float*  csr_nrm = (float*)alloc((size_t)E * 4);
  float*  agg1    = (float*)alloc((size_t)N * F0 * 4);
  float*  h       = (float*)alloc((size_t)N * F1 * 4);
  float*  agg2    = (float*)alloc((size_t)N * F1 * 4);
  double* gsum    = (double*)alloc(64 * 8);
  double* gsumsq  = (double*)alloc(64 * 8);
  float*  scalef  = (float*)alloc(64 * 4);
  float*  shiftf  = (float*)alloc(64 * 4);
  (void)ws_size; (void)n_in; (void)out_size;

  int bN = (N + 255) / 256;
  int bE = (E + 255) / 256;
  int bW = (N + 3) / 4;             // wave-per-node kernels, 256 threads = 4 waves
  int n4 = (N * F1) / 4;
  int b4 = (n4 + 255) / 256;

  k_init<<<bN, 256, 0, stream>>>(deg, cnt, gsum, gsumsq, N);
  k_deg<<<bE, 256, 0, stream>>>(col, ew, deg, cnt, E);
  k_dinv<<<bN, 256, 0, stream>>>(deg, N);
  k_scan1<<<NB, 1024, 0, stream>>>(cnt, offs, bsum, N);
  k_scan2<<<1, 64, 0, stream>>>(bsum, NB);
  k_scan3<<<NB, 1024, 0, stream>>>(offs, cnt, bsum, N, E);
  k_fill<<<bE, 256, 0, stream>>>(row, col, ew, deg, cnt, csr_src, csr_nrm, E);
  k_agg1<<<bW, 256, 0, stream>>>(x, offs, csr_src, csr_nrm, deg, agg1, N);
  k_gemm1<<<bW, 256, 0, stream>>>(agg1, W1, b1, h, N);
  k_bn_stats<<<1024, 256, 0, stream>>>(h, gsum, gsumsq, N * F1);
  k_bn_final<<<1, 64, 0, stream>>>(gsum, gsumsq, gamma, beta, scalef, shiftf, N);
  k_bn_relu<<<b4, 256, 0, stream>>>(h, scalef, shiftf, n4);
  k_agg2<<<bW, 256, 0, stream>>>(h, offs, csr_src, csr_nrm, deg, agg2, N);
  k_gemm2<<<bW, 256, 0, stream>>>(agg2, W2, b2, out, N);
}

// Round 2
// 490.474 us; speedup vs baseline: 1.6352x; 1.6352x over previous
//
#include <hip/hip_runtime.h>

#define F0 11
#define F1 64
#define F2 128
#define TN2 128   // nodes per block in k_gemm2

// ---------------- init: deg=1 (self loop), cnt=0, zero BN stats ----------------
__global__ void k_init(float* __restrict__ deg, int* __restrict__ cnt,
                       double* __restrict__ gsum, double* __restrict__ gsumsq, int n) {
  int i = blockIdx.x * blockDim.x + threadIdx.x;
  if (i < n) { deg[i] = 1.0f; cnt[i] = 0; }
  if (i < 64) { gsum[i] = 0.0; gsumsq[i] = 0.0; }
}

// ---------------- weighted degree + in-degree histogram ----------------
__global__ void k_deg(const int* __restrict__ col, const float* __restrict__ w,
                      float* __restrict__ deg, int* __restrict__ cnt, int E) {
  int e = blockIdx.x * blockDim.x + threadIdx.x;
  if (e >= E) return;
  int c = col[e];
  atomicAdd(&deg[c], w[e]);
  atomicAdd(&cnt[c], 1);
}

// deg -> dinv (deg >= 1 always because of self loops)
__global__ void k_dinv(float* __restrict__ deg, int n) {
  int i = blockIdx.x * blockDim.x + threadIdx.x;
  if (i < n) deg[i] = rsqrtf(deg[i]);
}

// ---------------- exclusive scan of cnt -> offs ----------------
__global__ void k_scan1(const int* __restrict__ cnt, int* __restrict__ offs,
                        int* __restrict__ bsum, int n) {
  __shared__ int s[1024];
  int tid = threadIdx.x;
  int i = blockIdx.x * 1024 + tid;
  int v = (i < n) ? cnt[i] : 0;
  s[tid] = v;
  __syncthreads();
  for (int d = 1; d < 1024; d <<= 1) {
    int t = (tid >= d) ? s[tid - d] : 0;
    __syncthreads();
    s[tid] += t;
    __syncthreads();
  }
  if (i < n) offs[i] = s[tid] - v;
  if (tid == 1023) bsum[blockIdx.x] = s[1023];
}

// parallel single-block scan of block sums (nb <= a few hundred)
__global__ void k_scan2(int* __restrict__ bsum, int nb) {
  __shared__ int s[256];
  __shared__ int carry;
  int t = threadIdx.x;
  if (t == 0) carry = 0;
  __syncthreads();
  for (int base = 0; base < nb; base += 256) {
    int v = (base + t < nb) ? bsum[base + t] : 0;
    s[t] = v;
    __syncthreads();
    for (int d = 1; d < 256; d <<= 1) {
      int x = (t >= d) ? s[t - d] : 0;
      __syncthreads();
      s[t] += x;
      __syncthreads();
    }
    int total = s[255];
    if (base + t < nb) bsum[base + t] = carry + s[t] - v;  // exclusive
    __syncthreads();
    if (t == 0) carry += total;
    __syncthreads();
  }
}

__global__ void k_scan3(int* __restrict__ offs, int* __restrict__ cursor,
                        const int* __restrict__ bsum, int n, int total) {
  int i = blockIdx.x * 1024 + threadIdx.x;
  if (i < n) {
    int v = offs[i] + bsum[blockIdx.x];
    offs[i] = v;
    cursor[i] = v;
  }
  if (i == 0) offs[n] = total;
}

// ---------------- CSR fill ----------------
__global__ void k_fill(const int* __restrict__ row, const int* __restrict__ col,
                       const float* __restrict__ w, const float* __restrict__ dinv,
                       int* __restrict__ cursor, int* __restrict__ csr_src,
                       float* __restrict__ csr_nrm, int E) {
  int e = blockIdx.x * blockDim.x + threadIdx.x;
  if (e >= E) return;
  int c = col[e], r = row[e];
  int pos = atomicAdd(&cursor[c], 1);
  csr_src[pos] = r;
  csr_nrm[pos] = dinv[r] * w[e] * dinv[c];
}

// ---------------- layer-1 aggregation (11 features), wave per node, chunked ----------------
__global__ void k_agg1(const float* __restrict__ x, const int* __restrict__ offs,
                       const int* __restrict__ csr_src, const float* __restrict__ csr_nrm,
                       const float* __restrict__ dinv, float* __restrict__ agg1, int n) {
  __shared__ int   s_src[4][64];
  __shared__ float s_nrm[4][64];
  int tid = threadIdx.x;
  int wv = tid >> 6;
  int lane = tid & 63;
  int wid = (blockIdx.x * blockDim.x + tid) >> 6;
  if (wid >= n) return;
  float di = dinv[wid];
  float a0 = 0.f, a1 = 0.f, a2 = 0.f, a3 = 0.f;
  if (lane < F0) a0 = di * di * x[wid * F0 + lane];   // self loop
  int s = offs[wid], e = offs[wid + 1];
  for (int base = s; base < e; base += 64) {
    int m = e - base; if (m > 64) m = 64;
    if (lane < m) {
      s_src[wv][lane] = csr_src[base + lane];
      s_nrm[wv][lane] = csr_nrm[base + lane];
    }
    int j = 0;
    for (; j + 4 <= m; j += 4) {
      int r0 = s_src[wv][j + 0], r1 = s_src[wv][j + 1];
      int r2 = s_src[wv][j + 2], r3 = s_src[wv][j + 3];
      float m0 = s_nrm[wv][j + 0], m1 = s_nrm[wv][j + 1];
      float m2 = s_nrm[wv][j + 2], m3 = s_nrm[wv][j + 3];
      if (lane < F0) {
        a0 += m0 * x[(size_t)r0 * F0 + lane];
        a1 += m1 * x[(size_t)r1 * F0 + lane];
        a2 += m2 * x[(size_t)r2 * F0 + lane];
        a3 += m3 * x[(size_t)r3 * F0 + lane];
      }
    }
    for (; j < m; j++) {
      int r = s_src[wv][j];
      float nm = s_nrm[wv][j];
      if (lane < F0) a0 += nm * x[(size_t)r * F0 + lane];
    }
  }
  if (lane < F0) agg1[wid * F0 + lane] = (a0 + a1) + (a2 + a3);
}

// ---------------- h = agg1 @ W1 + b1, wave per node, shfl broadcast ----------------
__global__ void k_gemm1(const float* __restrict__ agg1, const float* __restrict__ W1,
                        const float* __restrict__ b1, float* __restrict__ h, int n) {
  __shared__ float Ws[F0 * F1];
  __shared__ float bs[F1];
  int t = threadIdx.x;
  for (int i = t; i < F0 * F1; i += blockDim.x) Ws[i] = W1[i];
  if (t < F1) bs[t] = b1[t];
  __syncthreads();
  int wid = (blockIdx.x * blockDim.x + t) >> 6;
  int lane = t & 63;
  if (wid >= n) return;
  float av = (lane < F0) ? agg1[wid * F0 + lane] : 0.f;  // coalesced row load
  float acc = bs[lane];
#pragma unroll
  for (int k = 0; k < F0; k++) acc += __shfl(av, k) * Ws[k * F1 + lane];
  h[wid * F1 + lane] = acc;
}

// ---------------- BatchNorm statistics ----------------
__global__ void k_bn_stats(const float* __restrict__ h, double* __restrict__ gsum,
                           double* __restrict__ gsumsq, int total) {
  int t = threadIdx.x;
  int idx = blockIdx.x * blockDim.x + t;
  int stride = gridDim.x * blockDim.x;   // multiple of 64
  float s = 0.0f, q = 0.0f;
  for (int i = idx; i < total; i += stride) {
    float v = h[i];
    s += v; q += v * v;
  }
  __shared__ float ss[256], qq[256];
  ss[t] = s; qq[t] = q;
  __syncthreads();
  if (t < 64) {
    float S = ss[t] + ss[t + 64] + ss[t + 128] + ss[t + 192];
    float Q = qq[t] + qq[t + 64] + qq[t + 128] + qq[t + 192];
    atomicAdd(&gsum[t], (double)S);
    atomicAdd(&gsumsq[t], (double)Q);
  }
}

__global__ void k_bn_final(const double* __restrict__ gsum, const double* __restrict__ gsumsq,
                           const float* __restrict__ gamma, const float* __restrict__ beta,
                           float* __restrict__ scalef, float* __restrict__ shiftf, int n) {
  int f = threadIdx.x;
  if (f >= 64) return;
  double mean = gsum[f] / (double)n;
  double var = gsumsq[f] / (double)n - mean * mean;
  if (var < 0.0) var = 0.0;
  float scale = gamma[f] * (float)(1.0 / sqrt(var + 1e-5));
  scalef[f] = scale;
  shiftf[f] = beta[f] - (float)mean * scale;
}

// ---------------- normalize + ReLU in place (float4) ----------------
__global__ void k_bn_relu(float* __restrict__ h, const float* __restrict__ scalef,
                          const float* __restrict__ shiftf, int n4) {
  int i = blockIdx.x * blockDim.x + threadIdx.x;
  if (i >= n4) return;
  float4 v = ((float4*)h)[i];
  int f = (i * 4) & 63;
  v.x = fmaxf(0.0f, v.x * scalef[f + 0] + shiftf[f + 0]);
  v.y = fmaxf(0.0f, v.y * scalef[f + 1] + shiftf[f + 1]);
  v.z = fmaxf(0.0f, v.z * scalef[f + 2] + shiftf[f + 2]);
  v.w = fmaxf(0.0f, v.w * scalef[f + 3] + shiftf[f + 3]);
  ((float4*)h)[i] = v;
}

// ---------------- layer-2 aggregation (64 features), wave per node, chunked ----------------
__global__ void k_agg2(const float* __restrict__ h, const int* __restrict__ offs,
                       const int* __restrict__ csr_src, const float* __restrict__ csr_nrm,
                       const float* __restrict__ dinv, float* __restrict__ agg2, int n) {
  __shared__ int   s_src[4][64];
  __shared__ float s_nrm[4][64];
  int tid = threadIdx.x;
  int wv = tid >> 6;
  int lane = tid & 63;
  int wid = (blockIdx.x * blockDim.x + tid) >> 6;
  if (wid >= n) return;
  float di = dinv[wid];
  float a0 = di * di * h[(size_t)wid * F1 + lane];   // self loop
  float a1 = 0.f, a2 = 0.f, a3 = 0.f;
  int s = offs[wid], e = offs[wid + 1];
  for (int base = s; base < e; base += 64) {
    int m = e - base; if (m > 64) m = 64;
    if (lane < m) {
      s_src[wv][lane] = csr_src[base + lane];
      s_nrm[wv][lane] = csr_nrm[base + lane];
    }
    int j = 0;
    for (; j + 4 <= m; j += 4) {
      int r0 = s_src[wv][j + 0], r1 = s_src[wv][j + 1];
      int r2 = s_src[wv][j + 2], r3 = s_src[wv][j + 3];
      float m0 = s_nrm[wv][j + 0], m1 = s_nrm[wv][j + 1];
      float m2 = s_nrm[wv][j + 2], m3 = s_nrm[wv][j + 3];
      a0 += m0 * h[(size_t)r0 * F1 + lane];
      a1 += m1 * h[(size_t)r1 * F1 + lane];
      a2 += m2 * h[(size_t)r2 * F1 + lane];
      a3 += m3 * h[(size_t)r3 * F1 + lane];
    }
    for (; j < m; j++) {
      int r = s_src[wv][j];
      float nm = s_nrm[wv][j];
      a0 += nm * h[(size_t)r * F1 + lane];
    }
  }
  agg2[(size_t)wid * F1 + lane] = (a0 + a1) + (a2 + a3);
}

// ---------------- out = agg2 @ W2 + b2, register-tiled GEMM ----------------
// Block: 256 threads, 128 nodes. LDS: Ws[64][128] + As[64][128] = 64 KiB.
// Thread (t): feats f0=(t&15)*8, nodes n0=(t>>4)*8 -> 8x8 register tile.
__global__ __launch_bounds__(256) void k_gemm2(const float* __restrict__ agg2,
                                               const float* __restrict__ W2,
                                               const float* __restrict__ b2,
                                               float* __restrict__ out, int n) {
  __shared__ float Ws[F1 * F2];     // [k][f], 32 KiB
  __shared__ float As[F1][TN2];     // [k][node], 32 KiB
  int t = threadIdx.x;
  // stage W2 (coalesced float4)
  for (int i = t; i < F1 * F2 / 4; i += 256) ((float4*)Ws)[i] = ((const float4*)W2)[i];
  // stage A transposed: thread -> node=t&127, k-half=(t>>7)*32
  int nb = blockIdx.x * TN2;
  int node = t & 127;
  int kh = (t >> 7) * 32;
  int gnode = nb + node;
  if (gnode < n) {
    const float4* src = (const float4*)(agg2 + (size_t)gnode * F1 + kh);
#pragma unroll
    for (int j = 0; j < 8; j++) {
      float4 v = src[j];
      As[kh + j * 4 + 0][node] = v.x;
      As[kh + j * 4 + 1][node] = v.y;
      As[kh + j * 4 + 2][node] = v.z;
      As[kh + j * 4 + 3][node] = v.w;
    }
  } else {
#pragma unroll
    for (int j = 0; j < 8; j++) {
      As[kh + j * 4 + 0][node] = 0.f;
      As[kh + j * 4 + 1][node] = 0.f;
      As[kh + j * 4 + 2][node] = 0.f;
      As[kh + j * 4 + 3][node] = 0.f;
    }
  }
  __syncthreads();

  int f0 = (t & 15) * 8;
  int n0 = (t >> 4) * 8;
  float acc[8][8];
  float bv[8];
#pragma unroll
  for (int j = 0; j < 8; j++) bv[j] = b2[f0 + j];
#pragma unroll
  for (int i = 0; i < 8; i++)
#pragma unroll
    for (int j = 0; j < 8; j++) acc[i][j] = bv[j];

#pragma unroll 4
  for (int k = 0; k < F1; k++) {
    float4 a0 = *(const float4*)&As[k][n0];
    float4 a1 = *(const float4*)&As[k][n0 + 4];
    float4 w0 = *(const float4*)&Ws[k * F2 + f0];
    float4 w1 = *(const float4*)&Ws[k * F2 + f0 + 4];
    float a[8] = {a0.x, a0.y, a0.z, a0.w, a1.x, a1.y, a1.z, a1.w};
    float w[8] = {w0.x, w0.y, w0.z, w0.w, w1.x, w1.y, w1.z, w1.w};
#pragma unroll
    for (int i = 0; i < 8; i++)
#pragma unroll
      for (int j = 0; j < 8; j++) acc[i][j] += a[i] * w[j];
  }

  // store: per node i, two float4 at out[(nb+n0+i)*128 + f0 .. f0+7]
#pragma unroll
  for (int i = 0; i < 8; i++) {
    int gi = nb + n0 + i;
    if (gi < n) {
      float4 o0 = {acc[i][0], acc[i][1], acc[i][2], acc[i][3]};
      float4 o1 = {acc[i][4], acc[i][5], acc[i][6], acc[i][7]};
      *(float4*)&out[(size_t)gi * F2 + f0] = o0;
      *(float4*)&out[(size_t)gi * F2 + f0 + 4] = o1;
    }
  }
}

extern "C" void kernel_launch(void* const* d_in, const int* in_sizes, int n_in,
                              void* d_out, int out_size, void* d_ws, size_t ws_size,
                              hipStream_t stream) {
  const float* x     = (const float*)d_in[0];
  const int*   ei    = (const int*)d_in[1];
  const float* ew    = (const float*)d_in[2];
  const float* W1    = (const float*)d_in[3];
  const float* b1    = (const float*)d_in[4];
  const float* gamma = (const float*)d_in[5];
  const float* beta  = (const float*)d_in[6];
  const float* W2    = (const float*)d_in[7];
  const float* b2    = (const float*)d_in[8];
  float* out = (float*)d_out;

  int N = in_sizes[0] / F0;
  int E = in_sizes[1] / 2;
  const int* row = ei;
  const int* col = ei + E;
  if (N <= 0) return;

  // ---- workspace carve-up ----
  char* p = (char*)d_ws;
  auto alloc = [&](size_t bytes) -> void* {
    void* r = (void*)p;
    p += (bytes + 255) & ~(size_t)255;
    return r;
  };
  float*  deg     = (float*)alloc((size_t)N * 4);
  int*    cnt     = (int*)alloc((size_t)N * 4);
  int*    offs    = (int*)alloc((size_t)(N + 1) * 4);
  int     NB      = (N + 1023) / 1024;
  int*    bsum    = (int*)alloc((size_t)NB * 4);
  int*    csr_src = (int*)alloc((size_t)E * 4);
  float*  csr_nrm = (float*)alloc((size_t)E * 4);
  float*  agg1    = (float*)alloc((size_t)N * F0 * 4);
  float*  h       = (float*)alloc((size_t)N * F1 * 4);
  float*  agg2    = (float*)alloc((size_t)N * F1 * 4);
  double* gsum    = (double*)alloc(64 * 8);
  double* gsumsq  = (double*)alloc(64 * 8);
  float*  scalef  = (float*)alloc(64 * 4);
  float*  shiftf  = (float*)alloc(64 * 4);
  (void)ws_size; (void)n_in; (void)out_size;

  int bN = (N + 255) / 256;
  int bE = (E + 255) / 256;
  int bW = (N + 3) / 4;
  int n4 = (N * F1) / 4;
  int b4 = (n4 + 255) / 256;
  int bG2 = (N + TN2 - 1) / TN2;

  k_init<<<bN, 256, 0, stream>>>(deg, cnt, gsum, gsumsq, N);
  k_deg<<<bE, 256, 0, stream>>>(col, ew, deg, cnt, E);
  k_dinv<<<bN, 256, 0, stream>>>(deg, N);
  k_scan1<<<NB, 1024, 0, stream>>>(cnt, offs, bsum, N);
  k_scan2<<<1, 256, 0, stream>>>(bsum, NB);
  k_scan3<<<NB, 1024, 0, stream>>>(offs, cnt, bsum, N, E);
  k_fill<<<bE, 256, 0, stream>>>(row, col, ew, deg, cnt, csr_src, csr_nrm, E);
  k_agg1<<<bW, 256, 0, stream>>>(x, offs, csr_src, csr_nrm, deg, agg1, N);
  k_gemm1<<<bW, 256, 0, stream>>>(agg1, W1, b1, h, N);
  k_bn_stats<<<1024, 256, 0, stream>>>(h, gsum, gsumsq, N * F1);
  k_bn_final<<<1, 64, 0, stream>>>(gsum, gsumsq, gamma, beta, scalef, shiftf, N);
  k_bn_relu<<<b4, 256, 0, stream>>>(h, scalef, shiftf, n4);
  k_agg2<<<bW, 256, 0, stream>>>(h, offs, csr_src, csr_nrm, deg, agg2, N);
  k_gemm2<<<bG2, 256, 0, stream>>>(agg2, W2, b2, out, N);
}

// Round 3
// 327.644 us; speedup vs baseline: 2.4479x; 1.4970x over previous
//
#include <hip/hip_runtime.h>

#define F0 11
#define F1 64
#define F2 128
#define TN2 128   // nodes per block in k_gemm2

#define CHUNKS 32
#define BPR 25088        // bins (nodes) per range; even; WPR*4 = 50,176 B LDS
#define WPR (BPR / 2)    // packed u16 pairs per range

// ---------------- init: zero BN stats ----------------
__global__ void k_init(double* __restrict__ gsum, double* __restrict__ gsumsq) {
  int i = threadIdx.x;
  if (i < 64) { gsum[i] = 0.0; gsumsq[i] = 0.0; }
}

// ---------------- LDS-privatized histogram: partial[range][chunk][WPR] ----------------
__global__ __launch_bounds__(1024) void k_hist(const int* __restrict__ col,
                                               unsigned* __restrict__ partial,
                                               int E, int CE, int N) {
  __shared__ unsigned lds[WPR];
  int c = blockIdx.x, r = blockIdx.y;
  int lo = r * BPR;
  int hi = min(N, lo + BPR);
  int t = threadIdx.x;
  for (int i = t; i < WPR; i += 1024) lds[i] = 0;
  __syncthreads();
  int e0 = c * CE, e1 = min(E, e0 + CE);
  for (int e = e0 + t; e < e1; e += 1024) {
    int b = col[e];
    if (b >= lo && b < hi) {
      int local = b - lo;
      atomicAdd(&lds[local >> 1], 1u << (16 * (local & 1)));
    }
  }
  __syncthreads();
  unsigned* dst = partial + ((size_t)r * CHUNKS + c) * WPR;
  for (int i = t; i < WPR; i += 1024) dst[i] = lds[i];
}

// ---------------- per-bin prefix over chunks: rel[c][bin] (u16), cnt[bin] ----------------
__global__ void k_colprefix(const unsigned* __restrict__ partial,
                            unsigned short* __restrict__ rel,
                            int* __restrict__ cnt, int N, int npad) {
  int bin = blockIdx.x * blockDim.x + threadIdx.x;
  if (bin >= N) return;
  int r = bin / BPR, local = bin % BPR;
  int word = local >> 1, sh = 16 * (local & 1);
  const unsigned* p = partial + (size_t)r * CHUNKS * WPR + word;
  unsigned acc = 0;
  for (int c = 0; c < CHUNKS; c++) {
    unsigned v = (p[(size_t)c * WPR] >> sh) & 0xFFFFu;
    rel[(size_t)c * npad + bin] = (unsigned short)acc;
    acc += v;
  }
  cnt[bin] = (int)acc;
}

// ---------------- exclusive scan of cnt -> offs ----------------
__global__ void k_scan1(const int* __restrict__ cnt, int* __restrict__ offs,
                        int* __restrict__ bsum, int n) {
  __shared__ int s[1024];
  int tid = threadIdx.x;
  int i = blockIdx.x * 1024 + tid;
  int v = (i < n) ? cnt[i] : 0;
  s[tid] = v;
  __syncthreads();
  for (int d = 1; d < 1024; d <<= 1) {
    int t = (tid >= d) ? s[tid - d] : 0;
    __syncthreads();
    s[tid] += t;
    __syncthreads();
  }
  if (i < n) offs[i] = s[tid] - v;
  if (tid == 1023) bsum[blockIdx.x] = s[1023];
}

__global__ void k_scan2(int* __restrict__ bsum, int nb) {
  __shared__ int s[256];
  __shared__ int carry;
  int t = threadIdx.x;
  if (t == 0) carry = 0;
  __syncthreads();
  for (int base = 0; base < nb; base += 256) {
    int v = (base + t < nb) ? bsum[base + t] : 0;
    s[t] = v;
    __syncthreads();
    for (int d = 1; d < 256; d <<= 1) {
      int x = (t >= d) ? s[t - d] : 0;
      __syncthreads();
      s[t] += x;
      __syncthreads();
    }
    int total = s[255];
    if (base + t < nb) bsum[base + t] = carry + s[t] - v;
    __syncthreads();
    if (t == 0) carry += total;
    __syncthreads();
  }
}

__global__ void k_scan3(int* __restrict__ offs, const int* __restrict__ bsum,
                        int n, int total) {
  int i = blockIdx.x * 1024 + threadIdx.x;
  if (i < n) offs[i] += bsum[blockIdx.x];
  if (i == 0) offs[n] = total;
}

// ---------------- CSR fill: LDS cursors (u16 packed), zero global atomics ----------------
__global__ __launch_bounds__(1024) void k_fill(const int* __restrict__ row,
                                               const int* __restrict__ col,
                                               const float* __restrict__ w,
                                               const int* __restrict__ offs,
                                               const unsigned short* __restrict__ rel,
                                               uint2* __restrict__ csr8,
                                               int E, int CE, int N, int npad) {
  __shared__ unsigned cur[WPR];
  int c = blockIdx.x, r = blockIdx.y;
  int lo = r * BPR;
  int hi = min(N, lo + BPR);
  int t = threadIdx.x;
  // initial cursors = rel[c][lo..hi) as packed u16 pairs (4B-aligned: npad, lo even)
  const unsigned* rsrc = (const unsigned*)(rel + (size_t)c * npad + lo);
  int nw = (hi - lo + 1) >> 1;
  for (int i = t; i < nw; i += 1024) cur[i] = rsrc[i];
  __syncthreads();
  int e0 = c * CE, e1 = min(E, e0 + CE);
  for (int e = e0 + t; e < e1; e += 1024) {
    int b = col[e];
    if (b >= lo && b < hi) {
      int local = b - lo;
      int sh = 16 * (local & 1);
      unsigned old = atomicAdd(&cur[local >> 1], 1u << sh);
      unsigned myrel = (old >> sh) & 0xFFFFu;
      int pos = offs[b] + (int)myrel;
      csr8[pos] = make_uint2((unsigned)row[e], __float_as_uint(w[e]));
    }
  }
}

// ---------------- weighted degree -> dinv, wave per node ----------------
__global__ void k_deg2(const uint2* __restrict__ csr8, const int* __restrict__ offs,
                       float* __restrict__ dinv, int n) {
  int wid = (blockIdx.x * blockDim.x + threadIdx.x) >> 6;
  int lane = threadIdx.x & 63;
  if (wid >= n) return;
  int s = offs[wid], e = offs[wid + 1];
  float acc = 0.f;
  for (int k = s + lane; k < e; k += 64) acc += __uint_as_float(csr8[k].y);
#pragma unroll
  for (int d = 32; d > 0; d >>= 1) acc += __shfl_down(acc, d);
  if (lane == 0) dinv[wid] = rsqrtf(1.0f + acc);   // +1 = self loop weight
}

// ---------------- normalize: csr_src / csr_nrm, wave per node ----------------
__global__ void k_norm(const uint2* __restrict__ csr8, const int* __restrict__ offs,
                       const float* __restrict__ dinv, int* __restrict__ csr_src,
                       float* __restrict__ csr_nrm, int n) {
  int wid = (blockIdx.x * blockDim.x + threadIdx.x) >> 6;
  int lane = threadIdx.x & 63;
  if (wid >= n) return;
  float di = dinv[wid];
  int s = offs[wid], e = offs[wid + 1];
  for (int k = s + lane; k < e; k += 64) {
    uint2 v = csr8[k];
    int src = (int)v.x;
    float wv = __uint_as_float(v.y);
    csr_src[k] = src;
    csr_nrm[k] = dinv[src] * wv * di;
  }
}

// ---------------- layer-1 aggregation (11 features), wave per node, chunked ----------------
__global__ void k_agg1(const float* __restrict__ x, const int* __restrict__ offs,
                       const int* __restrict__ csr_src, const float* __restrict__ csr_nrm,
                       const float* __restrict__ dinv, float* __restrict__ agg1, int n) {
  __shared__ int   s_src[4][64];
  __shared__ float s_nrm[4][64];
  int tid = threadIdx.x;
  int wv = tid >> 6;
  int lane = tid & 63;
  int wid = (blockIdx.x * blockDim.x + tid) >> 6;
  if (wid >= n) return;
  float di = dinv[wid];
  float a0 = 0.f, a1 = 0.f, a2 = 0.f, a3 = 0.f;
  if (lane < F0) a0 = di * di * x[wid * F0 + lane];   // self loop
  int s = offs[wid], e = offs[wid + 1];
  for (int base = s; base < e; base += 64) {
    int m = e - base; if (m > 64) m = 64;
    if (lane < m) {
      s_src[wv][lane] = csr_src[base + lane];
      s_nrm[wv][lane] = csr_nrm[base + lane];
    }
    int j = 0;
    for (; j + 4 <= m; j += 4) {
      int r0 = s_src[wv][j + 0], r1 = s_src[wv][j + 1];
      int r2 = s_src[wv][j + 2], r3 = s_src[wv][j + 3];
      float m0 = s_nrm[wv][j + 0], m1 = s_nrm[wv][j + 1];
      float m2 = s_nrm[wv][j + 2], m3 = s_nrm[wv][j + 3];
      if (lane < F0) {
        a0 += m0 * x[(size_t)r0 * F0 + lane];
        a1 += m1 * x[(size_t)r1 * F0 + lane];
        a2 += m2 * x[(size_t)r2 * F0 + lane];
        a3 += m3 * x[(size_t)r3 * F0 + lane];
      }
    }
    for (; j < m; j++) {
      int r = s_src[wv][j];
      float nm = s_nrm[wv][j];
      if (lane < F0) a0 += nm * x[(size_t)r * F0 + lane];
    }
  }
  if (lane < F0) agg1[wid * F0 + lane] = (a0 + a1) + (a2 + a3);
}

// ---------------- h = agg1 @ W1 + b1, wave per node, shfl broadcast ----------------
__global__ void k_gemm1(const float* __restrict__ agg1, const float* __restrict__ W1,
                        const float* __restrict__ b1, float* __restrict__ h, int n) {
  __shared__ float Ws[F0 * F1];
  __shared__ float bs[F1];
  int t = threadIdx.x;
  for (int i = t; i < F0 * F1; i += blockDim.x) Ws[i] = W1[i];
  if (t < F1) bs[t] = b1[t];
  __syncthreads();
  int wid = (blockIdx.x * blockDim.x + t) >> 6;
  int lane = t & 63;
  if (wid >= n) return;
  float av = (lane < F0) ? agg1[wid * F0 + lane] : 0.f;
  float acc = bs[lane];
#pragma unroll
  for (int k = 0; k < F0; k++) acc += __shfl(av, k) * Ws[k * F1 + lane];
  h[wid * F1 + lane] = acc;
}

// ---------------- BatchNorm statistics ----------------
__global__ void k_bn_stats(const float* __restrict__ h, double* __restrict__ gsum,
                           double* __restrict__ gsumsq, int total) {
  int t = threadIdx.x;
  int idx = blockIdx.x * blockDim.x + t;
  int stride = gridDim.x * blockDim.x;
  float s = 0.0f, q = 0.0f;
  for (int i = idx; i < total; i += stride) {
    float v = h[i];
    s += v; q += v * v;
  }
  __shared__ float ss[256], qq[256];
  ss[t] = s; qq[t] = q;
  __syncthreads();
  if (t < 64) {
    float S = ss[t] + ss[t + 64] + ss[t + 128] + ss[t + 192];
    float Q = qq[t] + qq[t + 64] + qq[t + 128] + qq[t + 192];
    atomicAdd(&gsum[t], (double)S);
    atomicAdd(&gsumsq[t], (double)Q);
  }
}

__global__ void k_bn_final(const double* __restrict__ gsum, const double* __restrict__ gsumsq,
                           const float* __restrict__ gamma, const float* __restrict__ beta,
                           float* __restrict__ scalef, float* __restrict__ shiftf, int n) {
  int f = threadIdx.x;
  if (f >= 64) return;
  double mean = gsum[f] / (double)n;
  double var = gsumsq[f] / (double)n - mean * mean;
  if (var < 0.0) var = 0.0;
  float scale = gamma[f] * (float)(1.0 / sqrt(var + 1e-5));
  scalef[f] = scale;
  shiftf[f] = beta[f] - (float)mean * scale;
}

// ---------------- normalize + ReLU in place (float4) ----------------
__global__ void k_bn_relu(float* __restrict__ h, const float* __restrict__ scalef,
                          const float* __restrict__ shiftf, int n4) {
  int i = blockIdx.x * blockDim.x + threadIdx.x;
  if (i >= n4) return;
  float4 v = ((float4*)h)[i];
  int f = (i * 4) & 63;
  v.x = fmaxf(0.0f, v.x * scalef[f + 0] + shiftf[f + 0]);
  v.y = fmaxf(0.0f, v.y * scalef[f + 1] + shiftf[f + 1]);
  v.z = fmaxf(0.0f, v.z * scalef[f + 2] + shiftf[f + 2]);
  v.w = fmaxf(0.0f, v.w * scalef[f + 3] + shiftf[f + 3]);
  ((float4*)h)[i] = v;
}

// ---------------- layer-2 aggregation (64 features), wave per node, chunked ----------------
__global__ void k_agg2(const float* __restrict__ h, const int* __restrict__ offs,
                       const int* __restrict__ csr_src, const float* __restrict__ csr_nrm,
                       const float* __restrict__ dinv, float* __restrict__ agg2, int n) {
  __shared__ int   s_src[4][64];
  __shared__ float s_nrm[4][64];
  int tid = threadIdx.x;
  int wv = tid >> 6;
  int lane = tid & 63;
  int wid = (blockIdx.x * blockDim.x + tid) >> 6;
  if (wid >= n) return;
  float di = dinv[wid];
  float a0 = di * di * h[(size_t)wid * F1 + lane];
  float a1 = 0.f, a2 = 0.f, a3 = 0.f;
  int s = offs[wid], e = offs[wid + 1];
  for (int base = s; base < e; base += 64) {
    int m = e - base; if (m > 64) m = 64;
    if (lane < m) {
      s_src[wv][lane] = csr_src[base + lane];
      s_nrm[wv][lane] = csr_nrm[base + lane];
    }
    int j = 0;
    for (; j + 4 <= m; j += 4) {
      int r0 = s_src[wv][j + 0], r1 = s_src[wv][j + 1];
      int r2 = s_src[wv][j + 2], r3 = s_src[wv][j + 3];
      float m0 = s_nrm[wv][j + 0], m1 = s_nrm[wv][j + 1];
      float m2 = s_nrm[wv][j + 2], m3 = s_nrm[wv][j + 3];
      a0 += m0 * h[(size_t)r0 * F1 + lane];
      a1 += m1 * h[(size_t)r1 * F1 + lane];
      a2 += m2 * h[(size_t)r2 * F1 + lane];
      a3 += m3 * h[(size_t)r3 * F1 + lane];
    }
    for (; j < m; j++) {
      int r = s_src[wv][j];
      float nm = s_nrm[wv][j];
      a0 += nm * h[(size_t)r * F1 + lane];
    }
  }
  agg2[(size_t)wid * F1 + lane] = (a0 + a1) + (a2 + a3);
}

// ---------------- out = agg2 @ W2 + b2, register-tiled GEMM ----------------
__global__ __launch_bounds__(256) void k_gemm2(const float* __restrict__ agg2,
                                               const float* __restrict__ W2,
                                               const float* __restrict__ b2,
                                               float* __restrict__ out, int n) {
  __shared__ float Ws[F1 * F2];
  __shared__ float As[F1][TN2];
  int t = threadIdx.x;
  for (int i = t; i < F1 * F2 / 4; i += 256) ((float4*)Ws)[i] = ((const float4*)W2)[i];
  int nb = blockIdx.x * TN2;
  int node = t & 127;
  int kh = (t >> 7) * 32;
  int gnode = nb + node;
  if (gnode < n) {
    const float4* src = (const float4*)(agg2 + (size_t)gnode * F1 + kh);
#pragma unroll
    for (int j = 0; j < 8; j++) {
      float4 v = src[j];
      As[kh + j * 4 + 0][node] = v.x;
      As[kh + j * 4 + 1][node] = v.y;
      As[kh + j * 4 + 2][node] = v.z;
      As[kh + j * 4 + 3][node] = v.w;
    }
  } else {
#pragma unroll
    for (int j = 0; j < 8; j++) {
      As[kh + j * 4 + 0][node] = 0.f;
      As[kh + j * 4 + 1][node] = 0.f;
      As[kh + j * 4 + 2][node] = 0.f;
      As[kh + j * 4 + 3][node] = 0.f;
    }
  }
  __syncthreads();

  int f0 = (t & 15) * 8;
  int n0 = (t >> 4) * 8;
  float acc[8][8];
  float bv[8];
#pragma unroll
  for (int j = 0; j < 8; j++) bv[j] = b2[f0 + j];
#pragma unroll
  for (int i = 0; i < 8; i++)
#pragma unroll
    for (int j = 0; j < 8; j++) acc[i][j] = bv[j];

#pragma unroll 4
  for (int k = 0; k < F1; k++) {
    float4 a0 = *(const float4*)&As[k][n0];
    float4 a1 = *(const float4*)&As[k][n0 + 4];
    float4 w0 = *(const float4*)&Ws[k * F2 + f0];
    float4 w1 = *(const float4*)&Ws[k * F2 + f0 + 4];
    float a[8] = {a0.x, a0.y, a0.z, a0.w, a1.x, a1.y, a1.z, a1.w};
    float w[8] = {w0.x, w0.y, w0.z, w0.w, w1.x, w1.y, w1.z, w1.w};
#pragma unroll
    for (int i = 0; i < 8; i++)
#pragma unroll
      for (int j = 0; j < 8; j++) acc[i][j] += a[i] * w[j];
  }

#pragma unroll
  for (int i = 0; i < 8; i++) {
    int gi = nb + n0 + i;
    if (gi < n) {
      float4 o0 = {acc[i][0], acc[i][1], acc[i][2], acc[i][3]};
      float4 o1 = {acc[i][4], acc[i][5], acc[i][6], acc[i][7]};
      *(float4*)&out[(size_t)gi * F2 + f0] = o0;
      *(float4*)&out[(size_t)gi * F2 + f0 + 4] = o1;
    }
  }
}

extern "C" void kernel_launch(void* const* d_in, const int* in_sizes, int n_in,
                              void* d_out, int out_size, void* d_ws, size_t ws_size,
                              hipStream_t stream) {
  const float* x     = (const float*)d_in[0];
  const int*   ei    = (const int*)d_in[1];
  const float* ew    = (const float*)d_in[2];
  const float* W1    = (const float*)d_in[3];
  const float* b1    = (const float*)d_in[4];
  const float* gamma = (const float*)d_in[5];
  const float* beta  = (const float*)d_in[6];
  const float* W2    = (const float*)d_in[7];
  const float* b2    = (const float*)d_in[8];
  float* out = (float*)d_out;

  int N = in_sizes[0] / F0;
  int E = in_sizes[1] / 2;
  const int* row = ei;
  const int* col = ei + E;
  if (N <= 0) return;

  int CE = (E + CHUNKS - 1) / CHUNKS;
  int RANGES = (N + BPR - 1) / BPR;
  int npad = RANGES * BPR;

  // ---- workspace carve-up (~82 MB) ----
  char* p = (char*)d_ws;
  auto alloc = [&](size_t bytes) -> void* {
    void* r = (void*)p;
    p += (bytes + 255) & ~(size_t)255;
    return r;
  };
  size_t partial_bytes = (size_t)RANGES * CHUNKS * WPR * 4;
  size_t rel_bytes     = (size_t)CHUNKS * npad * 2;
  size_t eb            = (size_t)E * 4;

  float*          dinv    = (float*)alloc((size_t)N * 4);
  int*            cnt     = (int*)alloc((size_t)N * 4);
  int*            offs    = (int*)alloc((size_t)(N + 1) * 4);
  int             NB      = (N + 1023) / 1024;
  int*            bsum    = (int*)alloc((size_t)NB * 4);
  uint2*          csr8    = (uint2*)alloc((size_t)E * 8);
  unsigned*       partial = (unsigned*)alloc(partial_bytes > eb ? partial_bytes : eb);
  unsigned short* rel     = (unsigned short*)alloc(rel_bytes > eb ? rel_bytes : eb);
  int*            csr_src = (int*)partial;     // overlay: partial dead after colprefix
  float*          csr_nrm = (float*)rel;       // overlay: rel dead after fill
  float*          agg1    = (float*)alloc((size_t)N * F0 * 4);
  float*          h       = (float*)alloc((size_t)N * F1 * 4);
  float*          agg2    = (float*)alloc((size_t)N * F1 * 4);
  double*         gsum    = (double*)alloc(64 * 8);
  double*         gsumsq  = (double*)alloc(64 * 8);
  float*          scalef  = (float*)alloc(64 * 4);
  float*          shiftf  = (float*)alloc(64 * 4);
  (void)ws_size; (void)n_in; (void)out_size;

  int bW = (N + 3) / 4;
  int n4 = (N * F1) / 4;
  int b4 = (n4 + 255) / 256;
  int bG2 = (N + TN2 - 1) / TN2;
  dim3 gRC(CHUNKS, RANGES);

  k_init<<<1, 64, 0, stream>>>(gsum, gsumsq);
  k_hist<<<gRC, 1024, 0, stream>>>(col, partial, E, CE, N);
  k_colprefix<<<(N + 255) / 256, 256, 0, stream>>>(partial, rel, cnt, N, npad);
  k_scan1<<<NB, 1024, 0, stream>>>(cnt, offs, bsum, N);
  k_scan2<<<1, 256, 0, stream>>>(bsum, NB);
  k_scan3<<<NB, 1024, 0, stream>>>(offs, bsum, N, E);
  k_fill<<<gRC, 1024, 0, stream>>>(row, col, ew, offs, rel, csr8, E, CE, N, npad);
  k_deg2<<<bW, 256, 0, stream>>>(csr8, offs, dinv, N);
  k_norm<<<bW, 256, 0, stream>>>(csr8, offs, dinv, csr_src, csr_nrm, N);
  k_agg1<<<bW, 256, 0, stream>>>(x, offs, csr_src, csr_nrm, dinv, agg1, N);
  k_gemm1<<<bW, 256, 0, stream>>>(agg1, W1, b1, h, N);
  k_bn_stats<<<1024, 256, 0, stream>>>(h, gsum, gsumsq, N * F1);
  k_bn_final<<<1, 64, 0, stream>>>(gsum, gsumsq, gamma, beta, scalef, shiftf, N);
  k_bn_relu<<<b4, 256, 0, stream>>>(h, scalef, shiftf, n4);
  k_agg2<<<bW, 256, 0, stream>>>(h, offs, csr_src, csr_nrm, dinv, agg2, N);
  k_gemm2<<<bG2, 256, 0, stream>>>(agg2, W2, b2, out, N);
}